// Round 36
// baseline (144.135 us; speedup 1.0000x reference)
//
#include <hip/hip_runtime.h>
#include <hip/hip_bf16.h>

#define N_ROWS 65536
#define DIM 64
#define KC 2048
#define NPHH 16                 // phases of 64 codes per K-half
#define DECAY_F 0.99f
#define OMD_F 0.01f
#define EPS_F 1e-5f
#define MARGIN 0.005f

typedef short  s16x8  __attribute__((ext_vector_type(8)));
typedef __bf16 bf16x8 __attribute__((ext_vector_type(8)));
typedef float  f32x4v __attribute__((ext_vector_type(4)));

__device__ __forceinline__ bf16x8 as_bf(s16x8 v) { return __builtin_bit_cast(bf16x8, v); }

// ws layout (float units). EH/EL are 2048*64 bf16 = 65536 floats EACH.
// EH/EL hold -2*embed split (power-of-2 scale: precision identical).
static constexpr size_t WS_E2       = 0;        // f32 [2048]
static constexpr size_t WS_SMOOTH   = 2048;     // f32 [2048]
static constexpr size_t WS_OFFS     = 4096;     // i32 [2048]
static constexpr size_t WS_ROWIDS   = 6144;     // i32 [65536] row|code<<16 (ends 71680)
static constexpr size_t WS_EH       = 71680;    // bf16 [2048*64] (ends 137216)
static constexpr size_t WS_EL       = 137216;   // bf16 [2048*64] (ends 202752)
static constexpr size_t WS_COUNTS   = 202752;   // i32 [2048]   <- zeroed in prep_e
static constexpr size_t WS_CURS     = 204800;   // i32 [2048]
static constexpr size_t WS_LOSS     = 206848;   // f32 [1]
static constexpr size_t WS_FLAGCNT  = 206849;   // i32 [1]
static constexpr size_t WS_ESUM     = 206852;   // f32 [2048*64] <- zeroed in prep_e
static constexpr size_t WS_FLAGLIST = 337924;   // i32 [65536] (ends 403460)
static constexpr size_t WS_ZERO_CNT = 4098;     // counts+curs+loss+flagcnt

__device__ __forceinline__ unsigned short bf16_rne(float f) {
    unsigned u = __float_as_uint(f);
    return (unsigned short)((u + 0x7FFFu + ((u >> 16) & 1u)) >> 16);
}

// wave per code: lane = dim. eh/el = bf16 split of (-2*e); e2 via shfl reduce.
// Also zeroes counts/curs/loss/flagcnt AND esum (1 float per thread, 131072 total).
__global__ __launch_bounds__(256) void vq_prep_e_kernel(
    const float* __restrict__ embed, float* __restrict__ ws) {
    const int tid = threadIdx.x;
    const int lane = tid & 63;
    const int k = blockIdx.x * 4 + (tid >> 6);

    const int gtid = blockIdx.x * 256 + tid;
    if (gtid < (int)WS_ZERO_CNT) ws[WS_COUNTS + gtid] = 0.f;
    ws[WS_ESUM + gtid] = 0.f;          // grid = 131072 threads = esum size

    float v = embed[(size_t)k * DIM + lane];
    float m2v = -2.f * v;
    unsigned short hb = bf16_rne(m2v);
    float hf = __uint_as_float((unsigned)hb << 16);
    unsigned short lb = bf16_rne(m2v - hf);
    ((short*)(ws + WS_EH))[(size_t)k * DIM + lane] = (short)hb;
    ((short*)(ws + WS_EL))[(size_t)k * DIM + lane] = (short)lb;

    float sq = v * v;
#pragma unroll
    for (int off = 32; off > 0; off >>= 1)
        sq += __shfl_down(sq, off, 64);
    if (lane == 0) ws[WS_E2 + k] = sq;
}

// block = 8 waves (512 threads) x 128 rows; waves K-SPLIT: waves 0-3 scan
// codes [0,1024), waves 4-7 scan [1024,2048). 4 waves/SIMD (LDS-bound).
// DEFERRED-SELECT pipeline (R33). amdgpu_waves_per_eu(4,4) pins the
// allocator's wave target to the LDS-bound residency -> 128-VGPR budget,
// keeping accA/accB in registers (R33's default 64-VGPR choice spilled).
__global__ __launch_bounds__(512, 4) __attribute__((amdgpu_waves_per_eu(4, 4)))
void vq_mfma_kernel(
    const float* __restrict__ x,
    const float* __restrict__ embed,
    float* __restrict__ ws,
    float* __restrict__ out_q,
    float* __restrict__ out_ind) {
    __shared__ __attribute__((aligned(16))) short tile_lds[2][2][16][512]; // 64 KB
    __shared__ __attribute__((aligned(16))) float e2_lds[KC];              // 8 KB
    __shared__ float mb1[128], mb2[128];
    __shared__ int   mi1[128];

    const int tid = threadIdx.x;
    const int lane = tid & 63;
    const int w = tid >> 6;         // 0..7
    const int kh = w >> 2;          // K-half
    const int wq = w & 3;           // wave-quad role
    const int row0 = blockIdx.x * 128 + wq * 32;
    const int cr = lane & 15;       // A row = code ; B col = x row
    const int g = lane >> 4;        // k-group / C reg-row group

    // stage e2 into LDS (2048 floats, 1 float4 per thread)
    {
        const float4* s4p = reinterpret_cast<const float4*>(ws + WS_E2);
        *reinterpret_cast<float4*>(&e2_lds[tid * 4]) = s4p[tid];
    }

    // B-frags: rows row0+f*16+cr, split hi/lo, two K=32 chunks
    s16x8 xh[2][2], xl[2][2];
#pragma unroll
    for (int f = 0; f < 2; ++f) {
#pragma unroll
        for (int kc = 0; kc < 2; ++kc) {
            const float4* p4 = reinterpret_cast<const float4*>(
                x + (size_t)(row0 + f * 16 + cr) * DIM + kc * 32 + g * 8);
            float4 u = p4[0], v = p4[1];
            s16x8 h, l;
            unsigned short hb;
            hb = bf16_rne(u.x); h[0] = (short)hb; l[0] = (short)bf16_rne(u.x - __uint_as_float((unsigned)hb << 16));
            hb = bf16_rne(u.y); h[1] = (short)hb; l[1] = (short)bf16_rne(u.y - __uint_as_float((unsigned)hb << 16));
            hb = bf16_rne(u.z); h[2] = (short)hb; l[2] = (short)bf16_rne(u.z - __uint_as_float((unsigned)hb << 16));
            hb = bf16_rne(u.w); h[3] = (short)hb; l[3] = (short)bf16_rne(u.w - __uint_as_float((unsigned)hb << 16));
            hb = bf16_rne(v.x); h[4] = (short)hb; l[4] = (short)bf16_rne(v.x - __uint_as_float((unsigned)hb << 16));
            hb = bf16_rne(v.y); h[5] = (short)hb; l[5] = (short)bf16_rne(v.y - __uint_as_float((unsigned)hb << 16));
            hb = bf16_rne(v.z); h[6] = (short)hb; l[6] = (short)bf16_rne(v.z - __uint_as_float((unsigned)hb << 16));
            hb = bf16_rne(v.w); h[7] = (short)hb; l[7] = (short)bf16_rne(v.w - __uint_as_float((unsigned)hb << 16));
            xh[f][kc] = h; xl[f][kc] = l;
        }
    }

    const short* ehp = (const short*)(ws + WS_EH);
    const short* elp = (const short*)(ws + WS_EL);

    // wave (kh,wq) stages matrix-type wq for its half's sub-tiles:
    // m0=eh d0-31, m1=eh d32-63, m2=el d0-31, m3=el d32-63
    const short* mat_base = ((wq < 2) ? ehp : elp) + (wq & 1) * 32;

#define STAGE(buf, ph)                                                                  \
    {                                                                                   \
        _Pragma("unroll")                                                               \
        for (int s4 = 0; s4 < 4; ++s4) {                                                \
            const short* gsrc = mat_base +                                              \
                (size_t)(((kh * NPHH + (ph)) * 64) + s4 * 16 + cr) * DIM + g * 8;       \
            __builtin_amdgcn_global_load_lds(                                           \
                (const __attribute__((address_space(1))) void*)gsrc,                    \
                (__attribute__((address_space(3))) void*)(&tile_lds[(buf)][kh][s4 * 4 + wq][0]), \
                16, 0, 0);                                                              \
        }                                                                               \
    }

    STAGE(0, 0);
    __syncthreads();

    float b1[2] = {__builtin_inff(), __builtin_inff()};
    float b2[2] = {__builtin_inff(), __builtin_inff()};
    int   i1[2] = {0, 0};

    f32x4v accA[4][2], accB[4][2];

#define MFMA_PHASE(ph, WACC)                                                            \
    {                                                                                   \
        const int cur_ = (ph) & 1;                                                      \
        if ((ph) + 1 < NPHH) STAGE(cur_ ^ 1, (ph) + 1);                                 \
        __builtin_amdgcn_s_setprio(1);                                                  \
        _Pragma("unroll")                                                               \
        for (int s = 0; s < 4; ++s) {                                                   \
            s16x8 eh0 = *(const s16x8*)(&tile_lds[cur_][kh][s * 4 + 0][lane * 8]);      \
            s16x8 eh1 = *(const s16x8*)(&tile_lds[cur_][kh][s * 4 + 1][lane * 8]);      \
            s16x8 el0 = *(const s16x8*)(&tile_lds[cur_][kh][s * 4 + 2][lane * 8]);      \
            s16x8 el1 = *(const s16x8*)(&tile_lds[cur_][kh][s * 4 + 3][lane * 8]);      \
            const int kb_ = (kh * NPHH + (ph)) * 64 + s * 16 + g * 4;                   \
            f32x4v e2v = *reinterpret_cast<const f32x4v*>(&e2_lds[kb_]);                \
            _Pragma("unroll")                                                           \
            for (int f = 0; f < 2; ++f) {                                               \
                f32x4v a = e2v;                                                         \
                a = __builtin_amdgcn_mfma_f32_16x16x32_bf16(as_bf(eh0), as_bf(xh[f][0]), a, 0, 0, 0); \
                a = __builtin_amdgcn_mfma_f32_16x16x32_bf16(as_bf(eh1), as_bf(xh[f][1]), a, 0, 0, 0); \
                a = __builtin_amdgcn_mfma_f32_16x16x32_bf16(as_bf(el0), as_bf(xh[f][0]), a, 0, 0, 0); \
                a = __builtin_amdgcn_mfma_f32_16x16x32_bf16(as_bf(el1), as_bf(xh[f][1]), a, 0, 0, 0); \
                a = __builtin_amdgcn_mfma_f32_16x16x32_bf16(as_bf(eh0), as_bf(xl[f][0]), a, 0, 0, 0); \
                a = __builtin_amdgcn_mfma_f32_16x16x32_bf16(as_bf(eh1), as_bf(xl[f][1]), a, 0, 0, 0); \
                WACC[s][f] = a;                                                         \
            }                                                                           \
        }                                                                               \
        __builtin_amdgcn_s_setprio(0);                                                  \
    }

#define SELECT_PHASE(ph, RACC)                                                          \
    {                                                                                   \
        _Pragma("unroll")                                                               \
        for (int s = 0; s < 4; ++s) {                                                   \
            const int kb_ = (kh * NPHH + (ph)) * 64 + s * 16 + g * 4;                   \
            _Pragma("unroll")                                                           \
            for (int f = 0; f < 2; ++f) {                                               \
                _Pragma("unroll")                                                       \
                for (int r = 0; r < 4; ++r) {                                           \
                    float dd = RACC[s][f][r];                                           \
                    b2[f] = __builtin_amdgcn_fmed3f(b1[f], b2[f], dd);                  \
                    if (dd < b1[f]) { b1[f] = dd; i1[f] = kb_ + r; }                    \
                }                                                                       \
            }                                                                           \
        }                                                                               \
    }

    MFMA_PHASE(0, accA);
    __syncthreads();
    for (int ph = 1; ph < NPHH - 1; ph += 2) {
        MFMA_PHASE(ph, accB);
        SELECT_PHASE(ph - 1, accA);
        __syncthreads();
        MFMA_PHASE(ph + 1, accA);
        SELECT_PHASE(ph, accB);
        __syncthreads();
    }
    MFMA_PHASE(NPHH - 1, accB);
    SELECT_PHASE(NPHH - 2, accA);
    SELECT_PHASE(NPHH - 1, accB);
#undef MFMA_PHASE
#undef SELECT_PHASE
#undef STAGE

    // merge the 4 k-groups (lanes cr, cr+16, cr+32, cr+48), per B-frag
#pragma unroll
    for (int f = 0; f < 2; ++f) {
#pragma unroll
        for (int mask = 16; mask <= 32; mask <<= 1) {
            float ob1 = __shfl_xor(b1[f], mask, 64);
            int   oi1 = __shfl_xor(i1[f], mask, 64);
            float ob2 = __shfl_xor(b2[f], mask, 64);
            float nb2 = fminf(fminf(b2[f], ob2), fmaxf(b1[f], ob1));
            if (ob1 < b1[f] || (ob1 == b1[f] && oi1 < i1[f])) { b1[f] = ob1; i1[f] = oi1; }
            b2[f] = nb2;
        }
    }

    // cross-half merge via LDS: upper waves publish, lower waves combine.
    if (kh == 1 && g == 0) {
#pragma unroll
        for (int f = 0; f < 2; ++f) {
            int rib = wq * 32 + f * 16 + cr;
            mb1[rib] = b1[f];
            mb2[rib] = b2[f];
            mi1[rib] = i1[f];
        }
    }
    __syncthreads();
    if (kh == 1) return;   // upper waves done (no further barriers below)

    float gap[2];
#pragma unroll
    for (int f = 0; f < 2; ++f) {
        int rib = wq * 32 + f * 16 + cr;
        float ob1 = mb1[rib];
        float ob2 = mb2[rib];
        int   oi1 = mi1[rib];
        float nb2 = fminf(fminf(b2[f], ob2), fmaxf(b1[f], ob1));
        if (ob1 < b1[f]) { b1[f] = ob1; i1[f] = oi1; }  // upper codes > lower: strict <
        b2[f] = nb2;
        gap[f] = b2[f] - b1[f];
        if (g == 0) {
            int row = row0 + f * 16 + cr;
            out_ind[row] = (float)i1[f];
            if (gap[f] < MARGIN) {
                int p = atomicAdd((int*)(ws + WS_FLAGCNT), 1);
                if (p >= 0 && p < N_ROWS) ((int*)(ws + WS_FLAGLIST))[p] = row;
            } else {
                atomicAdd((int*)(ws + WS_COUNTS) + i1[f], 1);
            }
        }
    }

    // fused epilogue: out_q gather + exact-f32 loss for UNFLAGGED rows
    float lossacc = 0.f;
#pragma unroll
    for (int f = 0; f < 2; ++f) {
#pragma unroll
        for (int r = 0; r < 16; ++r) {
            int   fi_r = __shfl(i1[f], r, 64);
            float gp_r = __shfl(gap[f], r, 64);
            if (gp_r >= MARGIN) {          // wave-uniform
                int row = row0 + f * 16 + r;
                float q  = embed[(size_t)fi_r * DIM + lane];
                float xv = x[(size_t)row * DIM + lane];
                out_q[(size_t)row * DIM + lane] = q;
                float d = q - xv;
                lossacc = fmaf(d, d, lossacc);
            }
        }
    }
#pragma unroll
    for (int off = 32; off > 0; off >>= 1)
        lossacc += __shfl_down(lossacc, off, 64);
    if (lane == 0) atomicAdd(ws + WS_LOSS, lossacc);
}

// exact f32 re-argmin for flagged rows + their epilogue (out_q, loss, counts).
// grid 2048, LDS tree reduction (no serial 256-entry min).
__global__ __launch_bounds__(256) void vq_rescore_kernel(
    const float* __restrict__ x,
    const float* __restrict__ embed,
    float* __restrict__ ws,
    float* __restrict__ out_q,
    float* __restrict__ out_ind) {
    __shared__ float xs[DIM];
    __shared__ float bd[256];
    __shared__ int   bi[256];
    __shared__ int   smi;
    const int tid = threadIdx.x;
    int cnt = ((const int*)(ws + WS_FLAGCNT))[0];
    cnt = (cnt < 0) ? 0 : ((cnt > N_ROWS) ? N_ROWS : cnt);
    const int* flags = (const int*)(ws + WS_FLAGLIST);

    for (int f = blockIdx.x; f < cnt; f += gridDim.x) {
        const int row = flags[f] & (N_ROWS - 1);
        if (tid < DIM) xs[tid] = x[(size_t)row * DIM + tid];
        __syncthreads();
        float lb = __builtin_inff(); int li = 0;
        for (int k = tid; k < KC; k += 256) {
            const float* e = embed + (size_t)k * DIM;
            float dot = 0.f;
#pragma unroll
            for (int d = 0; d < DIM; ++d) dot = fmaf(xs[d], e[d], dot);
            float dd = ws[WS_E2 + k] - 2.f * dot;
            if (dd < lb) { lb = dd; li = k; }   // k ascending per thread
        }
        bd[tid] = lb; bi[tid] = li;
        __syncthreads();
        for (int s = 128; s > 0; s >>= 1) {
            if (tid < s) {
                float ov = bd[tid + s]; int oi = bi[tid + s];
                if (ov < bd[tid] || (ov == bd[tid] && oi < bi[tid])) { bd[tid] = ov; bi[tid] = oi; }
            }
            __syncthreads();
        }
        if (tid == 0) {
            out_ind[row] = (float)bi[0];
            smi = bi[0];
            atomicAdd((int*)(ws + WS_COUNTS) + bi[0], 1);
        }
        __syncthreads();
        const int mi = smi;
        if (tid < DIM) {
            float q = embed[(size_t)mi * DIM + tid];
            float xv = xs[tid];
            out_q[(size_t)row * DIM + tid] = q;
            float d = q - xv;
            float ld = d * d;
#pragma unroll
            for (int off = 32; off > 0; off >>= 1)
                ld += __shfl_down(ld, off, 64);
            if (tid == 0) atomicAdd(ws + WS_LOSS, ld);
        }
        __syncthreads();
    }
}

// 1 block: exclusive prefix over counts -> offsets; laplace smoothing; loss out.
__global__ __launch_bounds__(256) void vq_prefix_kernel(
    const float* __restrict__ cluster_size,
    float* __restrict__ ws,
    float* __restrict__ out_loss) {
    __shared__ int   sscan[256];
    __shared__ float sred[256];
    const int tid = threadIdx.x;
    const int* counts = (const int*)(ws + WS_COUNTS);
    int* offs = (int*)(ws + WS_OFFS);

    int lc[8];
    int tot = 0;
    float csum = 0.f;
#pragma unroll
    for (int j = 0; j < 8; ++j) {
        lc[j] = counts[tid * 8 + j];
        tot += lc[j];
        csum += cluster_size[tid * 8 + j];
    }
    sscan[tid] = tot;
    sred[tid] = csum;
    __syncthreads();
    for (int off = 1; off < 256; off <<= 1) {
        int v = (tid >= off) ? sscan[tid - off] : 0;
        __syncthreads();
        sscan[tid] += v;
        __syncthreads();
    }
    for (int s = 128; s > 0; s >>= 1) {
        if (tid < s) sred[tid] += sred[tid + s];
        __syncthreads();
    }
    int run = sscan[tid] - tot;      // exclusive prefix
#pragma unroll
    for (int j = 0; j < 8; ++j) {
        offs[tid * 8 + j] = run;
        run += lc[j];
    }
    const float n = DECAY_F * sred[0] + OMD_F * (float)N_ROWS;
    const float scale = n / (n + (float)KC * EPS_F);
#pragma unroll
    for (int j = 0; j < 8; ++j) {
        int k = tid * 8 + j;
        float ncs = fmaf(OMD_F, (float)counts[k], DECAY_F * cluster_size[k]);
        ws[WS_SMOOTH + k] = (ncs + EPS_F) * scale;
    }
    if (tid == 0) out_loss[0] = ws[WS_LOSS] / (float)((size_t)N_ROWS * DIM);
}

// bucket-fill: (row | code<<16) grouped by code (pure scatter; esum zeroed in prep_e).
__global__ __launch_bounds__(256) void vq_fill_kernel(
    const float* __restrict__ out_ind,
    float* __restrict__ ws) {
    const int row = blockIdx.x * blockDim.x + threadIdx.x;
    const int fi = ((int)out_ind[row]) & (KC - 1);
    const int* offs = (const int*)(ws + WS_OFFS);
    int* curs = (int*)(ws + WS_CURS);
    int* rowids = (int*)(ws + WS_ROWIDS);
    int pos = atomicAdd(&curs[fi], 1);
    int idx = offs[fi] + pos;
    if (idx >= 0 && idx < N_ROWS) rowids[idx] = row | (fi << 16);
}

// skew-proof gather: each wave owns a 32-entry WINDOW of the sorted bucket
// array (2048 windows, grid 512 -> 2x TLP vs 64-entry windows). lane = dim.
// Depth-8 prefetch pipeline; wave-uniform segment flushes to esum.
__global__ __launch_bounds__(256) void vq_gather_kernel(
    const float* __restrict__ x,
    float* __restrict__ ws) {
    const int lane = threadIdx.x & 63;
    const int w = blockIdx.x * 4 + (threadIdx.x >> 6);   // window id, 2048 total
    const int* rowids = (const int*)(ws + WS_ROWIDS);
    float* esum = ws + WS_ESUM;

    const int e = rowids[w * 32 + (lane & 31)];   // entries in lanes 0..31 (dup 32..63)

    float pf[8];
#pragma unroll
    for (int j = 0; j < 8; ++j) {
        int rj = __shfl(e, j, 64) & 0xFFFF;
        pf[j] = x[(size_t)rj * DIM + lane];
    }

    float acc = 0.f;
    int kprev = (__shfl(e, 0, 64) >> 16) & (KC - 1);
#pragma unroll
    for (int i = 0; i < 32; ++i) {
        float v = pf[i & 7];
        if (i + 8 < 32) {
            int rn = __shfl(e, i + 8, 64) & 0xFFFF;
            pf[i & 7] = x[(size_t)rn * DIM + lane];
        }
        int k = (__shfl(e, i, 64) >> 16) & (KC - 1);
        if (k != kprev) {                     // wave-uniform branch
            atomicAdd(&esum[(size_t)kprev * DIM + lane], acc);
            acc = 0.f;
            kprev = k;
        }
        acc += v;
    }
    atomicAdd(&esum[(size_t)kprev * DIM + lane], acc);
}

// out_embed = (0.99*embed_avg + 0.01*esum) / smooth
__global__ __launch_bounds__(256) void vq_emb_kernel(
    const float* __restrict__ embed_avg,
    const float* __restrict__ ws,
    float* __restrict__ out_embed) {
    int i = blockIdx.x * blockDim.x + threadIdx.x;
    if (i >= KC * DIM) return;
    int k = i >> 6;
    float na = fmaf(OMD_F, ws[WS_ESUM + i], DECAY_F * embed_avg[i]);
    out_embed[i] = na / ws[WS_SMOOTH + k];
}

extern "C" void kernel_launch(void* const* d_in, const int* in_sizes, int n_in,
                              void* d_out, int out_size, void* d_ws, size_t ws_size,
                              hipStream_t stream) {
    const float* x            = (const float*)d_in[0];
    const float* embed        = (const float*)d_in[1];
    const float* embed_avg    = (const float*)d_in[2];
    const float* cluster_size = (const float*)d_in[3];

    float* out      = (float*)d_out;
    float* out_q    = out;                                  // [N*D]
    float* out_loss = out + (size_t)N_ROWS * DIM;           // [1]
    float* out_ind  = out_loss + 1;                         // [N]
    float* out_emb  = out_ind + N_ROWS;                     // [K*D]

    float* ws = (float*)d_ws;

    vq_prep_e_kernel<<<KC / 4, 256, 0, stream>>>(embed, ws);
    vq_mfma_kernel<<<N_ROWS / 128, 512, 0, stream>>>(x, embed, ws, out_q, out_ind);
    vq_rescore_kernel<<<2048, 256, 0, stream>>>(x, embed, ws, out_q, out_ind);
    vq_prefix_kernel<<<1, 256, 0, stream>>>(cluster_size, ws, out_loss);
    vq_fill_kernel<<<N_ROWS / 256, 256, 0, stream>>>(out_ind, ws);
    vq_gather_kernel<<<N_ROWS / 32 / 4, 256, 0, stream>>>(x, ws);
    vq_emb_kernel<<<(KC * DIM) / 256, 256, 0, stream>>>(embed_avg, ws, out_emb);
}

// Round 37
// 141.911 us; speedup vs baseline: 1.0157x; 1.0157x over previous
//
#include <hip/hip_runtime.h>
#include <hip/hip_bf16.h>

#define N_ROWS 65536
#define DIM 64
#define KC 2048
#define NPHH 16                 // phases of 64 codes per K-half
#define DECAY_F 0.99f
#define OMD_F 0.01f
#define EPS_F 1e-5f
#define MARGIN 0.005f

typedef short  s16x8  __attribute__((ext_vector_type(8)));
typedef __bf16 bf16x8 __attribute__((ext_vector_type(8)));
typedef float  f32x4v __attribute__((ext_vector_type(4)));

__device__ __forceinline__ bf16x8 as_bf(s16x8 v) { return __builtin_bit_cast(bf16x8, v); }

// ws layout (float units). EH/EL are 2048*64 bf16 = 65536 floats EACH.
// EH/EL hold -2*embed split (power-of-2 scale: precision identical).
static constexpr size_t WS_E2       = 0;        // f32 [2048]
static constexpr size_t WS_SMOOTH   = 2048;     // f32 [2048]
static constexpr size_t WS_OFFS     = 4096;     // i32 [2048]
static constexpr size_t WS_ROWIDS   = 6144;     // i32 [65536] row|code<<16 (ends 71680)
static constexpr size_t WS_EH       = 71680;    // bf16 [2048*64] (ends 137216)
static constexpr size_t WS_EL       = 137216;   // bf16 [2048*64] (ends 202752)
static constexpr size_t WS_COUNTS   = 202752;   // i32 [2048]   <- zeroed in prep_e
static constexpr size_t WS_CURS     = 204800;   // i32 [2048]
static constexpr size_t WS_LOSS     = 206848;   // f32 [1]
static constexpr size_t WS_FLAGCNT  = 206849;   // i32 [1]
static constexpr size_t WS_ESUM     = 206852;   // f32 [2048*64] <- zeroed in prep_e
static constexpr size_t WS_FLAGLIST = 337924;   // i32 [65536] (ends 403460)
static constexpr size_t WS_ZERO_CNT = 4098;     // counts+curs+loss+flagcnt

__device__ __forceinline__ unsigned short bf16_rne(float f) {
    unsigned u = __float_as_uint(f);
    return (unsigned short)((u + 0x7FFFu + ((u >> 16) & 1u)) >> 16);
}

// wave per code: lane = dim. eh/el = bf16 split of (-2*e); e2 via shfl reduce.
// Also zeroes counts/curs/loss/flagcnt AND esum (1 float per thread, 131072 total).
__global__ __launch_bounds__(256) void vq_prep_e_kernel(
    const float* __restrict__ embed, float* __restrict__ ws) {
    const int tid = threadIdx.x;
    const int lane = tid & 63;
    const int k = blockIdx.x * 4 + (tid >> 6);

    const int gtid = blockIdx.x * 256 + tid;
    if (gtid < (int)WS_ZERO_CNT) ws[WS_COUNTS + gtid] = 0.f;
    ws[WS_ESUM + gtid] = 0.f;          // grid = 131072 threads = esum size

    float v = embed[(size_t)k * DIM + lane];
    float m2v = -2.f * v;
    unsigned short hb = bf16_rne(m2v);
    float hf = __uint_as_float((unsigned)hb << 16);
    unsigned short lb = bf16_rne(m2v - hf);
    ((short*)(ws + WS_EH))[(size_t)k * DIM + lane] = (short)hb;
    ((short*)(ws + WS_EL))[(size_t)k * DIM + lane] = (short)lb;

    float sq = v * v;
#pragma unroll
    for (int off = 32; off > 0; off >>= 1)
        sq += __shfl_down(sq, off, 64);
    if (lane == 0) ws[WS_E2 + k] = sq;
}

// block = 8 waves (512 threads) x 128 rows; waves K-SPLIT: waves 0-3 scan
// codes [0,1024), waves 4-7 scan [1024,2048). 4 waves/SIMD (LDS-bound).
// HALF-DEFERRED SELECT: subtiles 0-1 select in-phase (overlaps subtiles
// 1-3's MFMA issue); subtiles 2-3 buffered (32 VGPRs/parity) and selected
// in the next phase's barrier interval. Fits 64-VGPR budget without spill.
__global__ __launch_bounds__(512, 4) void vq_mfma_kernel(
    const float* __restrict__ x,
    const float* __restrict__ embed,
    float* __restrict__ ws,
    float* __restrict__ out_q,
    float* __restrict__ out_ind) {
    __shared__ __attribute__((aligned(16))) short tile_lds[2][2][16][512]; // 64 KB
    __shared__ __attribute__((aligned(16))) float e2_lds[KC];              // 8 KB
    __shared__ float mb1[128], mb2[128];
    __shared__ int   mi1[128];

    const int tid = threadIdx.x;
    const int lane = tid & 63;
    const int w = tid >> 6;         // 0..7
    const int kh = w >> 2;          // K-half
    const int wq = w & 3;           // wave-quad role
    const int row0 = blockIdx.x * 128 + wq * 32;
    const int cr = lane & 15;       // A row = code ; B col = x row
    const int g = lane >> 4;        // k-group / C reg-row group

    // stage e2 into LDS (2048 floats, 1 float4 per thread)
    {
        const float4* s4p = reinterpret_cast<const float4*>(ws + WS_E2);
        *reinterpret_cast<float4*>(&e2_lds[tid * 4]) = s4p[tid];
    }

    // B-frags: rows row0+f*16+cr, split hi/lo, two K=32 chunks
    s16x8 xh[2][2], xl[2][2];
#pragma unroll
    for (int f = 0; f < 2; ++f) {
#pragma unroll
        for (int kc = 0; kc < 2; ++kc) {
            const float4* p4 = reinterpret_cast<const float4*>(
                x + (size_t)(row0 + f * 16 + cr) * DIM + kc * 32 + g * 8);
            float4 u = p4[0], v = p4[1];
            s16x8 h, l;
            unsigned short hb;
            hb = bf16_rne(u.x); h[0] = (short)hb; l[0] = (short)bf16_rne(u.x - __uint_as_float((unsigned)hb << 16));
            hb = bf16_rne(u.y); h[1] = (short)hb; l[1] = (short)bf16_rne(u.y - __uint_as_float((unsigned)hb << 16));
            hb = bf16_rne(u.z); h[2] = (short)hb; l[2] = (short)bf16_rne(u.z - __uint_as_float((unsigned)hb << 16));
            hb = bf16_rne(u.w); h[3] = (short)hb; l[3] = (short)bf16_rne(u.w - __uint_as_float((unsigned)hb << 16));
            hb = bf16_rne(v.x); h[4] = (short)hb; l[4] = (short)bf16_rne(v.x - __uint_as_float((unsigned)hb << 16));
            hb = bf16_rne(v.y); h[5] = (short)hb; l[5] = (short)bf16_rne(v.y - __uint_as_float((unsigned)hb << 16));
            hb = bf16_rne(v.z); h[6] = (short)hb; l[6] = (short)bf16_rne(v.z - __uint_as_float((unsigned)hb << 16));
            hb = bf16_rne(v.w); h[7] = (short)hb; l[7] = (short)bf16_rne(v.w - __uint_as_float((unsigned)hb << 16));
            xh[f][kc] = h; xl[f][kc] = l;
        }
    }

    const short* ehp = (const short*)(ws + WS_EH);
    const short* elp = (const short*)(ws + WS_EL);

    // wave (kh,wq) stages matrix-type wq for its half's sub-tiles:
    // m0=eh d0-31, m1=eh d32-63, m2=el d0-31, m3=el d32-63
    const short* mat_base = ((wq < 2) ? ehp : elp) + (wq & 1) * 32;

#define STAGE(buf, ph)                                                                  \
    {                                                                                   \
        _Pragma("unroll")                                                               \
        for (int s4 = 0; s4 < 4; ++s4) {                                                \
            const short* gsrc = mat_base +                                              \
                (size_t)(((kh * NPHH + (ph)) * 64) + s4 * 16 + cr) * DIM + g * 8;       \
            __builtin_amdgcn_global_load_lds(                                           \
                (const __attribute__((address_space(1))) void*)gsrc,                    \
                (__attribute__((address_space(3))) void*)(&tile_lds[(buf)][kh][s4 * 4 + wq][0]), \
                16, 0, 0);                                                              \
        }                                                                               \
    }

    STAGE(0, 0);
    __syncthreads();

    float b1[2] = {__builtin_inff(), __builtin_inff()};
    float b2[2] = {__builtin_inff(), __builtin_inff()};
    int   i1[2] = {0, 0};

    f32x4v accA[2][2], accB[2][2];   // subtiles 2-3 only (half-deferred)

#define SEL1(dd_, kidx_, f_)                                                            \
    {                                                                                   \
        b2[f_] = __builtin_amdgcn_fmed3f(b1[f_], b2[f_], (dd_));                        \
        if ((dd_) < b1[f_]) { b1[f_] = (dd_); i1[f_] = (kidx_); }                       \
    }

#define MFMA_PHASE(ph, WACC)                                                            \
    {                                                                                   \
        const int cur_ = (ph) & 1;                                                      \
        if ((ph) + 1 < NPHH) STAGE(cur_ ^ 1, (ph) + 1);                                 \
        __builtin_amdgcn_s_setprio(1);                                                  \
        _Pragma("unroll")                                                               \
        for (int s = 0; s < 4; ++s) {                                                   \
            s16x8 eh0 = *(const s16x8*)(&tile_lds[cur_][kh][s * 4 + 0][lane * 8]);      \
            s16x8 eh1 = *(const s16x8*)(&tile_lds[cur_][kh][s * 4 + 1][lane * 8]);      \
            s16x8 el0 = *(const s16x8*)(&tile_lds[cur_][kh][s * 4 + 2][lane * 8]);      \
            s16x8 el1 = *(const s16x8*)(&tile_lds[cur_][kh][s * 4 + 3][lane * 8]);      \
            const int kb_ = (kh * NPHH + (ph)) * 64 + s * 16 + g * 4;                   \
            f32x4v e2v = *reinterpret_cast<const f32x4v*>(&e2_lds[kb_]);                \
            _Pragma("unroll")                                                           \
            for (int f = 0; f < 2; ++f) {                                               \
                f32x4v a = e2v;                                                         \
                a = __builtin_amdgcn_mfma_f32_16x16x32_bf16(as_bf(eh0), as_bf(xh[f][0]), a, 0, 0, 0); \
                a = __builtin_amdgcn_mfma_f32_16x16x32_bf16(as_bf(eh1), as_bf(xh[f][1]), a, 0, 0, 0); \
                a = __builtin_amdgcn_mfma_f32_16x16x32_bf16(as_bf(el0), as_bf(xh[f][0]), a, 0, 0, 0); \
                a = __builtin_amdgcn_mfma_f32_16x16x32_bf16(as_bf(el1), as_bf(xh[f][1]), a, 0, 0, 0); \
                a = __builtin_amdgcn_mfma_f32_16x16x32_bf16(as_bf(eh0), as_bf(xl[f][0]), a, 0, 0, 0); \
                a = __builtin_amdgcn_mfma_f32_16x16x32_bf16(as_bf(eh1), as_bf(xl[f][1]), a, 0, 0, 0); \
                if (s < 2) {                                                            \
                    SEL1(a[0], kb_ + 0, f); SEL1(a[1], kb_ + 1, f);                     \
                    SEL1(a[2], kb_ + 2, f); SEL1(a[3], kb_ + 3, f);                     \
                } else {                                                                \
                    WACC[s - 2][f] = a;                                                 \
                }                                                                       \
            }                                                                           \
        }                                                                               \
        __builtin_amdgcn_s_setprio(0);                                                  \
    }

#define SELECT_PHASE(ph, RACC)                                                          \
    {                                                                                   \
        _Pragma("unroll")                                                               \
        for (int s = 2; s < 4; ++s) {                                                   \
            const int kb_ = (kh * NPHH + (ph)) * 64 + s * 16 + g * 4;                   \
            _Pragma("unroll")                                                           \
            for (int f = 0; f < 2; ++f) {                                               \
                _Pragma("unroll")                                                       \
                for (int r = 0; r < 4; ++r) {                                           \
                    float dd = RACC[s - 2][f][r];                                       \
                    SEL1(dd, kb_ + r, f);                                               \
                }                                                                       \
            }                                                                           \
        }                                                                               \
    }

    MFMA_PHASE(0, accA);
    __syncthreads();
    for (int ph = 1; ph < NPHH - 1; ph += 2) {
        MFMA_PHASE(ph, accB);
        SELECT_PHASE(ph - 1, accA);
        __syncthreads();
        MFMA_PHASE(ph + 1, accA);
        SELECT_PHASE(ph, accB);
        __syncthreads();
    }
    MFMA_PHASE(NPHH - 1, accB);
    SELECT_PHASE(NPHH - 2, accA);
    SELECT_PHASE(NPHH - 1, accB);
#undef MFMA_PHASE
#undef SELECT_PHASE
#undef SEL1
#undef STAGE

    // merge the 4 k-groups (lanes cr, cr+16, cr+32, cr+48), per B-frag
#pragma unroll
    for (int f = 0; f < 2; ++f) {
#pragma unroll
        for (int mask = 16; mask <= 32; mask <<= 1) {
            float ob1 = __shfl_xor(b1[f], mask, 64);
            int   oi1 = __shfl_xor(i1[f], mask, 64);
            float ob2 = __shfl_xor(b2[f], mask, 64);
            float nb2 = fminf(fminf(b2[f], ob2), fmaxf(b1[f], ob1));
            if (ob1 < b1[f] || (ob1 == b1[f] && oi1 < i1[f])) { b1[f] = ob1; i1[f] = oi1; }
            b2[f] = nb2;
        }
    }

    // cross-half merge via LDS: upper waves publish, lower waves combine.
    if (kh == 1 && g == 0) {
#pragma unroll
        for (int f = 0; f < 2; ++f) {
            int rib = wq * 32 + f * 16 + cr;
            mb1[rib] = b1[f];
            mb2[rib] = b2[f];
            mi1[rib] = i1[f];
        }
    }
    __syncthreads();
    if (kh == 1) return;   // upper waves done (no further barriers below)

    float gap[2];
#pragma unroll
    for (int f = 0; f < 2; ++f) {
        int rib = wq * 32 + f * 16 + cr;
        float ob1 = mb1[rib];
        float ob2 = mb2[rib];
        int   oi1 = mi1[rib];
        float nb2 = fminf(fminf(b2[f], ob2), fmaxf(b1[f], ob1));
        if (ob1 < b1[f]) { b1[f] = ob1; i1[f] = oi1; }  // upper codes > lower: strict <
        b2[f] = nb2;
        gap[f] = b2[f] - b1[f];
        if (g == 0) {
            int row = row0 + f * 16 + cr;
            out_ind[row] = (float)i1[f];
            if (gap[f] < MARGIN) {
                int p = atomicAdd((int*)(ws + WS_FLAGCNT), 1);
                if (p >= 0 && p < N_ROWS) ((int*)(ws + WS_FLAGLIST))[p] = row;
            } else {
                atomicAdd((int*)(ws + WS_COUNTS) + i1[f], 1);
            }
        }
    }

    // fused epilogue: out_q gather + exact-f32 loss for UNFLAGGED rows
    float lossacc = 0.f;
#pragma unroll
    for (int f = 0; f < 2; ++f) {
#pragma unroll
        for (int r = 0; r < 16; ++r) {
            int   fi_r = __shfl(i1[f], r, 64);
            float gp_r = __shfl(gap[f], r, 64);
            if (gp_r >= MARGIN) {          // wave-uniform
                int row = row0 + f * 16 + r;
                float q  = embed[(size_t)fi_r * DIM + lane];
                float xv = x[(size_t)row * DIM + lane];
                out_q[(size_t)row * DIM + lane] = q;
                float d = q - xv;
                lossacc = fmaf(d, d, lossacc);
            }
        }
    }
#pragma unroll
    for (int off = 32; off > 0; off >>= 1)
        lossacc += __shfl_down(lossacc, off, 64);
    if (lane == 0) atomicAdd(ws + WS_LOSS, lossacc);
}

// exact f32 re-argmin for flagged rows + their epilogue (out_q, loss, counts).
// grid 2048, LDS tree reduction (no serial 256-entry min).
__global__ __launch_bounds__(256) void vq_rescore_kernel(
    const float* __restrict__ x,
    const float* __restrict__ embed,
    float* __restrict__ ws,
    float* __restrict__ out_q,
    float* __restrict__ out_ind) {
    __shared__ float xs[DIM];
    __shared__ float bd[256];
    __shared__ int   bi[256];
    __shared__ int   smi;
    const int tid = threadIdx.x;
    int cnt = ((const int*)(ws + WS_FLAGCNT))[0];
    cnt = (cnt < 0) ? 0 : ((cnt > N_ROWS) ? N_ROWS : cnt);
    const int* flags = (const int*)(ws + WS_FLAGLIST);

    for (int f = blockIdx.x; f < cnt; f += gridDim.x) {
        const int row = flags[f] & (N_ROWS - 1);
        if (tid < DIM) xs[tid] = x[(size_t)row * DIM + tid];
        __syncthreads();
        float lb = __builtin_inff(); int li = 0;
        for (int k = tid; k < KC; k += 256) {
            const float* e = embed + (size_t)k * DIM;
            float dot = 0.f;
#pragma unroll
            for (int d = 0; d < DIM; ++d) dot = fmaf(xs[d], e[d], dot);
            float dd = ws[WS_E2 + k] - 2.f * dot;
            if (dd < lb) { lb = dd; li = k; }   // k ascending per thread
        }
        bd[tid] = lb; bi[tid] = li;
        __syncthreads();
        for (int s = 128; s > 0; s >>= 1) {
            if (tid < s) {
                float ov = bd[tid + s]; int oi = bi[tid + s];
                if (ov < bd[tid] || (ov == bd[tid] && oi < bi[tid])) { bd[tid] = ov; bi[tid] = oi; }
            }
            __syncthreads();
        }
        if (tid == 0) {
            out_ind[row] = (float)bi[0];
            smi = bi[0];
            atomicAdd((int*)(ws + WS_COUNTS) + bi[0], 1);
        }
        __syncthreads();
        const int mi = smi;
        if (tid < DIM) {
            float q = embed[(size_t)mi * DIM + tid];
            float xv = xs[tid];
            out_q[(size_t)row * DIM + tid] = q;
            float d = q - xv;
            float ld = d * d;
#pragma unroll
            for (int off = 32; off > 0; off >>= 1)
                ld += __shfl_down(ld, off, 64);
            if (tid == 0) atomicAdd(ws + WS_LOSS, ld);
        }
        __syncthreads();
    }
}

// 1 block: exclusive prefix over counts -> offsets; laplace smoothing; loss out.
__global__ __launch_bounds__(256) void vq_prefix_kernel(
    const float* __restrict__ cluster_size,
    float* __restrict__ ws,
    float* __restrict__ out_loss) {
    __shared__ int   sscan[256];
    __shared__ float sred[256];
    const int tid = threadIdx.x;
    const int* counts = (const int*)(ws + WS_COUNTS);
    int* offs = (int*)(ws + WS_OFFS);

    int lc[8];
    int tot = 0;
    float csum = 0.f;
#pragma unroll
    for (int j = 0; j < 8; ++j) {
        lc[j] = counts[tid * 8 + j];
        tot += lc[j];
        csum += cluster_size[tid * 8 + j];
    }
    sscan[tid] = tot;
    sred[tid] = csum;
    __syncthreads();
    for (int off = 1; off < 256; off <<= 1) {
        int v = (tid >= off) ? sscan[tid - off] : 0;
        __syncthreads();
        sscan[tid] += v;
        __syncthreads();
    }
    for (int s = 128; s > 0; s >>= 1) {
        if (tid < s) sred[tid] += sred[tid + s];
        __syncthreads();
    }
    int run = sscan[tid] - tot;      // exclusive prefix
#pragma unroll
    for (int j = 0; j < 8; ++j) {
        offs[tid * 8 + j] = run;
        run += lc[j];
    }
    const float n = DECAY_F * sred[0] + OMD_F * (float)N_ROWS;
    const float scale = n / (n + (float)KC * EPS_F);
#pragma unroll
    for (int j = 0; j < 8; ++j) {
        int k = tid * 8 + j;
        float ncs = fmaf(OMD_F, (float)counts[k], DECAY_F * cluster_size[k]);
        ws[WS_SMOOTH + k] = (ncs + EPS_F) * scale;
    }
    if (tid == 0) out_loss[0] = ws[WS_LOSS] / (float)((size_t)N_ROWS * DIM);
}

// bucket-fill: (row | code<<16) grouped by code (pure scatter; esum zeroed in prep_e).
__global__ __launch_bounds__(256) void vq_fill_kernel(
    const float* __restrict__ out_ind,
    float* __restrict__ ws) {
    const int row = blockIdx.x * blockDim.x + threadIdx.x;
    const int fi = ((int)out_ind[row]) & (KC - 1);
    const int* offs = (const int*)(ws + WS_OFFS);
    int* curs = (int*)(ws + WS_CURS);
    int* rowids = (int*)(ws + WS_ROWIDS);
    int pos = atomicAdd(&curs[fi], 1);
    int idx = offs[fi] + pos;
    if (idx >= 0 && idx < N_ROWS) rowids[idx] = row | (fi << 16);
}

// skew-proof gather: each wave owns a 32-entry WINDOW of the sorted bucket
// array (2048 windows, grid 512 -> 2x TLP vs 64-entry windows). lane = dim.
// Depth-8 prefetch pipeline; wave-uniform segment flushes to esum.
__global__ __launch_bounds__(256) void vq_gather_kernel(
    const float* __restrict__ x,
    float* __restrict__ ws) {
    const int lane = threadIdx.x & 63;
    const int w = blockIdx.x * 4 + (threadIdx.x >> 6);   // window id, 2048 total
    const int* rowids = (const int*)(ws + WS_ROWIDS);
    float* esum = ws + WS_ESUM;

    const int e = rowids[w * 32 + (lane & 31)];   // entries in lanes 0..31 (dup 32..63)

    float pf[8];
#pragma unroll
    for (int j = 0; j < 8; ++j) {
        int rj = __shfl(e, j, 64) & 0xFFFF;
        pf[j] = x[(size_t)rj * DIM + lane];
    }

    float acc = 0.f;
    int kprev = (__shfl(e, 0, 64) >> 16) & (KC - 1);
#pragma unroll
    for (int i = 0; i < 32; ++i) {
        float v = pf[i & 7];
        if (i + 8 < 32) {
            int rn = __shfl(e, i + 8, 64) & 0xFFFF;
            pf[i & 7] = x[(size_t)rn * DIM + lane];
        }
        int k = (__shfl(e, i, 64) >> 16) & (KC - 1);
        if (k != kprev) {                     // wave-uniform branch
            atomicAdd(&esum[(size_t)kprev * DIM + lane], acc);
            acc = 0.f;
            kprev = k;
        }
        acc += v;
    }
    atomicAdd(&esum[(size_t)kprev * DIM + lane], acc);
}

// out_embed = (0.99*embed_avg + 0.01*esum) / smooth
__global__ __launch_bounds__(256) void vq_emb_kernel(
    const float* __restrict__ embed_avg,
    const float* __restrict__ ws,
    float* __restrict__ out_embed) {
    int i = blockIdx.x * blockDim.x + threadIdx.x;
    if (i >= KC * DIM) return;
    int k = i >> 6;
    float na = fmaf(OMD_F, ws[WS_ESUM + i], DECAY_F * embed_avg[i]);
    out_embed[i] = na / ws[WS_SMOOTH + k];
}

extern "C" void kernel_launch(void* const* d_in, const int* in_sizes, int n_in,
                              void* d_out, int out_size, void* d_ws, size_t ws_size,
                              hipStream_t stream) {
    const float* x            = (const float*)d_in[0];
    const float* embed        = (const float*)d_in[1];
    const float* embed_avg    = (const float*)d_in[2];
    const float* cluster_size = (const float*)d_in[3];

    float* out      = (float*)d_out;
    float* out_q    = out;                                  // [N*D]
    float* out_loss = out + (size_t)N_ROWS * DIM;           // [1]
    float* out_ind  = out_loss + 1;                         // [N]
    float* out_emb  = out_ind + N_ROWS;                     // [K*D]

    float* ws = (float*)d_ws;

    vq_prep_e_kernel<<<KC / 4, 256, 0, stream>>>(embed, ws);
    vq_mfma_kernel<<<N_ROWS / 128, 512, 0, stream>>>(x, embed, ws, out_q, out_ind);
    vq_rescore_kernel<<<2048, 256, 0, stream>>>(x, embed, ws, out_q, out_ind);
    vq_prefix_kernel<<<1, 256, 0, stream>>>(cluster_size, ws, out_loss);
    vq_fill_kernel<<<N_ROWS / 256, 256, 0, stream>>>(out_ind, ws);
    vq_gather_kernel<<<N_ROWS / 32 / 4, 256, 0, stream>>>(x, ws);
    vq_emb_kernel<<<(KC * DIM) / 256, 256, 0, stream>>>(embed_avg, ws, out_emb);
}